// Round 1
// baseline (695.580 us; speedup 1.0000x reference)
//
#include <hip/hip_runtime.h>
#include <hip/hip_bf16.h>

// ScalarOut: h = silu(x @ w1^T + b1); res = h @ w2^T + b2; out = segment_sum(res, batch, 4096)
// x: [N,128] f32, batch: [N] int (sorted), w1: [64,128] f32, b1: [64], w2: [1,64], b2: [1]
// out: [4096] f32

typedef __attribute__((ext_vector_type(8))) short bf16x8;
typedef __attribute__((ext_vector_type(4))) float f32x4;

__device__ __forceinline__ unsigned short f2bf(float f) {
    unsigned u = __float_as_uint(f);
    u += 0x7fffu + ((u >> 16) & 1u);   // round-to-nearest-even
    return (unsigned short)(u >> 16);
}

__device__ __forceinline__ bf16x8 pack8(const float4 a, const float4 b) {
    bf16x8 r;
    r[0] = (short)f2bf(a.x); r[1] = (short)f2bf(a.y);
    r[2] = (short)f2bf(a.z); r[3] = (short)f2bf(a.w);
    r[4] = (short)f2bf(b.x); r[5] = (short)f2bf(b.y);
    r[6] = (short)f2bf(b.z); r[7] = (short)f2bf(b.w);
    return r;
}

__global__ void __launch_bounds__(256) scalar_out_mlp(
    const float* __restrict__ x, const int* __restrict__ batch,
    const float* __restrict__ w1, const float* __restrict__ b1,
    const float* __restrict__ w2, const float* __restrict__ b2,
    float* __restrict__ out, int n_nodes)
{
    const int tid  = threadIdx.x;
    const int wave = tid >> 6;      // 0..3
    const int l    = tid & 63;
    const int lr   = l & 15;        // row/col within 16
    const int lg   = l >> 4;        // k-group / node-subgroup

    // ---- Load weight fragments once per block (w1 is 32 KB, L2-hot) ----
    // B[k][n] = w1[n][k]; fragment: col n = t*16+lr, k = c*32 + lg*8 + i
    bf16x8 wf[4][4];
#pragma unroll
    for (int t = 0; t < 4; ++t) {
        const float* wrow = w1 + (t * 16 + lr) * 128;
#pragma unroll
        for (int c = 0; c < 4; ++c) {
            const float* p = wrow + c * 32 + lg * 8;
            float4 u0 = *reinterpret_cast<const float4*>(p);
            float4 u1 = *reinterpret_cast<const float4*>(p + 4);
            wf[t][c] = pack8(u0, u1);
        }
    }
    float b1v[4], w2v[4];
#pragma unroll
    for (int t = 0; t < 4; ++t) {
        b1v[t] = b1[t * 16 + lr];
        w2v[t] = w2[t * 16 + lr];
    }
    const float b2s = b2[0];

    const int ntiles      = n_nodes >> 4;          // 16 nodes per wave-tile
    const int waves_total = gridDim.x * 4;
    const int gwave       = blockIdx.x * 4 + wave;

    for (int tile = gwave; tile < ntiles; tile += waves_total) {
        const int r0 = tile << 4;
        // A fragment: row = r0+lr, k = c*32 + lg*8 + i (8 consecutive fp32)
        const float* xrow = x + (size_t)(r0 + lr) * 128 + lg * 8;

        bf16x8 af[4];
#pragma unroll
        for (int c = 0; c < 4; ++c) {
            float4 u0 = *reinterpret_cast<const float4*>(xrow + c * 32);
            float4 u1 = *reinterpret_cast<const float4*>(xrow + c * 32 + 4);
            af[c] = pack8(u0, u1);
        }

        f32x4 acc[4];
#pragma unroll
        for (int t = 0; t < 4; ++t) acc[t] = (f32x4){0.f, 0.f, 0.f, 0.f};

#pragma unroll
        for (int c = 0; c < 4; ++c)
#pragma unroll
            for (int t = 0; t < 4; ++t)
                acc[t] = __builtin_amdgcn_mfma_f32_16x16x32_bf16(af[c], wf[t][c], acc[t], 0, 0, 0);

        // C/D layout: col(hidden-in-tile) = lr, row(node-in-tile) = lg*4 + j
        float p[4];
#pragma unroll
        for (int j = 0; j < 4; ++j) {
            float s = 0.f;
#pragma unroll
            for (int t = 0; t < 4; ++t) {
                float h  = acc[t][j] + b1v[t];
                float sg = 1.f / (1.f + __expf(-h));
                s += h * sg * w2v[t];
            }
            p[j] = s;
        }
        // reduce over the 16 "hidden" lanes (same lg group)
#pragma unroll
        for (int j = 0; j < 4; ++j) {
            p[j] += __shfl_xor(p[j], 1, 16);
            p[j] += __shfl_xor(p[j], 2, 16);
            p[j] += __shfl_xor(p[j], 4, 16);
            p[j] += __shfl_xor(p[j], 8, 16);
        }
        // p[j] (uniform across lr) = layer2 pre-bias for node r0 + lg*4 + j

        const int bfirst = batch[r0];
        const int blast  = batch[r0 + 15];
        if (bfirst == blast) {
            // whole tile in one segment: single atomic
            float s = (p[0] + p[1] + p[2] + p[3]) + 4.f * b2s;
            s += __shfl_xor(s, 16, 64);
            s += __shfl_xor(s, 32, 64);
            if (l == 0) atomicAdd(&out[bfirst], s);
        } else {
            if (lr < 4) {
                const int j = lr;
                const int n = r0 + lg * 4 + j;
                atomicAdd(&out[batch[n]], p[j] + b2s);
            }
        }
    }
}

extern "C" void kernel_launch(void* const* d_in, const int* in_sizes, int n_in,
                              void* d_out, int out_size, void* d_ws, size_t ws_size,
                              hipStream_t stream) {
    const float* x     = (const float*)d_in[0];
    const int*   batch = (const int*)d_in[1];
    const float* w1    = (const float*)d_in[2];
    const float* b1    = (const float*)d_in[3];
    const float* w2    = (const float*)d_in[4];
    const float* b2    = (const float*)d_in[5];
    float* out = (float*)d_out;

    const int n_nodes = in_sizes[0] / 128;

    hipMemsetAsync(d_out, 0, (size_t)out_size * sizeof(float), stream);

    const int nblk = 1024;
    hipLaunchKernelGGL(scalar_out_mlp, dim3(nblk), dim3(256), 0, stream,
                       x, batch, w1, b1, w2, b2, out, n_nodes);
}

// Round 2
// 669.361 us; speedup vs baseline: 1.0392x; 1.0392x over previous
//
#include <hip/hip_runtime.h>
#include <hip/hip_bf16.h>

// ScalarOut: h = silu(x @ w1^T + b1); res = h @ w2^T + b2; out = segment_sum(res, batch, 4096)
// x: [N,128] f32, batch: [N] int (sorted), w1: [64,128] f32, b1: [64], w2: [1,64], b2: [1]

typedef __attribute__((ext_vector_type(8))) short bf16x8;
typedef __attribute__((ext_vector_type(4))) float f32x4;

__device__ __forceinline__ unsigned short f2bf(float f) {
    __hip_bfloat16 h = __float2bfloat16(f);   // RNE; compiler fuses pairs to v_cvt_pk_bf16_f32
    union { __hip_bfloat16 b; unsigned short u; } c; c.b = h;
    return c.u;
}

__device__ __forceinline__ bf16x8 pack8(const float4 a, const float4 b) {
    bf16x8 r;
    r[0] = (short)f2bf(a.x); r[1] = (short)f2bf(a.y);
    r[2] = (short)f2bf(a.z); r[3] = (short)f2bf(a.w);
    r[4] = (short)f2bf(b.x); r[5] = (short)f2bf(b.y);
    r[6] = (short)f2bf(b.z); r[7] = (short)f2bf(b.w);
    return r;
}

__global__ void __launch_bounds__(256) scalar_out_mlp(
    const float* __restrict__ x, const int* __restrict__ batch,
    const float* __restrict__ w1, const float* __restrict__ b1,
    const float* __restrict__ w2, const float* __restrict__ b2,
    float* __restrict__ out, int n_nodes)
{
    const int tid  = threadIdx.x;
    const int wave = tid >> 6;
    const int l    = tid & 63;
    const int lr   = l & 15;        // hidden-col / node-row within 16
    const int lg   = l >> 4;        // k-group

    // Weight fragments, resident in VGPRs (w1 = 32 KB, L2-hot after first block).
    // B[k][n] = w1[n][k]; col n = t*16+lr, k = c*32 + lg*8 + i
    bf16x8 wf[4][4];
#pragma unroll
    for (int t = 0; t < 4; ++t) {
        const float* wrow = w1 + (t * 16 + lr) * 128;
#pragma unroll
        for (int c = 0; c < 4; ++c) {
            const float* p = wrow + c * 32 + lg * 8;
            wf[t][c] = pack8(*reinterpret_cast<const float4*>(p),
                             *reinterpret_cast<const float4*>(p + 4));
        }
    }
    float b1v[4], w2v[4];
#pragma unroll
    for (int t = 0; t < 4; ++t) {
        b1v[t] = b1[t * 16 + lr];
        w2v[t] = w2[t * 16 + lr];
    }
    const float b2s = b2[0];

    const int ntiles = n_nodes >> 4;                 // 16 nodes per wave-tile
    const int stride = gridDim.x * 4;
    int tile = blockIdx.x * 4 + wave;

    float4 cur[8];
    if (tile < ntiles) {
        const float* p = x + (size_t)((tile << 4) + lr) * 128 + lg * 8;
#pragma unroll
        for (int c = 0; c < 4; ++c) {
            cur[2 * c]     = *reinterpret_cast<const float4*>(p + c * 32);
            cur[2 * c + 1] = *reinterpret_cast<const float4*>(p + c * 32 + 4);
        }
    }

    while (tile < ntiles) {
        const int nt = tile + stride;
        float4 nxt[8];
        if (nt < ntiles) {                           // prefetch next grid-stride tile
            const float* p = x + (size_t)((nt << 4) + lr) * 128 + lg * 8;
#pragma unroll
            for (int c = 0; c < 4; ++c) {
                nxt[2 * c]     = *reinterpret_cast<const float4*>(p + c * 32);
                nxt[2 * c + 1] = *reinterpret_cast<const float4*>(p + c * 32 + 4);
            }
        }

        const int r0     = tile << 4;
        const int bfirst = batch[r0];
        const int blast  = batch[r0 + 15];

        bf16x8 af[4];
#pragma unroll
        for (int c = 0; c < 4; ++c) af[c] = pack8(cur[2 * c], cur[2 * c + 1]);

        f32x4 acc[4];
#pragma unroll
        for (int t = 0; t < 4; ++t) acc[t] = (f32x4){0.f, 0.f, 0.f, 0.f};
#pragma unroll
        for (int c = 0; c < 4; ++c)
#pragma unroll
            for (int t = 0; t < 4; ++t)
                acc[t] = __builtin_amdgcn_mfma_f32_16x16x32_bf16(af[c], wf[t][c], acc[t], 0, 0, 0);

        // C/D: col(hidden) = lr, row(node-in-tile) = lg*4 + j
        float p4[4];
#pragma unroll
        for (int j = 0; j < 4; ++j) {
            float s = 0.f;
#pragma unroll
            for (int t = 0; t < 4; ++t) {
                float h  = acc[t][j] + b1v[t];
                float sg = __builtin_amdgcn_rcpf(1.f + __expf(-h));
                s += h * sg * w2v[t];
            }
            p4[j] = s;
        }
#pragma unroll
        for (int j = 0; j < 4; ++j) {                // reduce over 16 hidden lanes
            p4[j] += __shfl_xor(p4[j], 1, 16);
            p4[j] += __shfl_xor(p4[j], 2, 16);
            p4[j] += __shfl_xor(p4[j], 4, 16);
            p4[j] += __shfl_xor(p4[j], 8, 16);
        }

        if (bfirst == blast) {                       // whole tile in one segment
            float s = (p4[0] + p4[1] + p4[2] + p4[3]) + 4.f * b2s;
            s += __shfl_xor(s, 16, 64);
            s += __shfl_xor(s, 32, 64);
            if (l == 0) atomicAdd(&out[bfirst], s);
        } else {
            if (lr < 4) {
                const int j = lr;
                const int n = r0 + lg * 4 + j;
                atomicAdd(&out[batch[n]], p4[j] + b2s);
            }
        }

#pragma unroll
        for (int i = 0; i < 8; ++i) cur[i] = nxt[i];
        tile = nt;
    }
}

extern "C" void kernel_launch(void* const* d_in, const int* in_sizes, int n_in,
                              void* d_out, int out_size, void* d_ws, size_t ws_size,
                              hipStream_t stream) {
    const float* x     = (const float*)d_in[0];
    const int*   batch = (const int*)d_in[1];
    const float* w1    = (const float*)d_in[2];
    const float* b1    = (const float*)d_in[3];
    const float* w2    = (const float*)d_in[4];
    const float* b2    = (const float*)d_in[5];
    float* out = (float*)d_out;

    const int n_nodes = in_sizes[0] / 128;

    hipMemsetAsync(d_out, 0, (size_t)out_size * sizeof(float), stream);

    const int nblk = 2048;
    hipLaunchKernelGGL(scalar_out_mlp, dim3(nblk), dim3(256), 0, stream,
                       x, batch, w1, b1, w2, b2, out, n_nodes);
}